// Round 11
// baseline (80.833 us; speedup 1.0000x reference)
//
#include <hip/hip_runtime.h>

#define ROWS_ 131072      // S*N*B = 16*256*32
#define NNZ_  524288
#define E4_   64          // f32x4 per output row (E=256)
#define LOG2NNZ_ 19       // 2^19 == NNZ_
#define CONV_BLOCKS_ 6250 // 50000*256 f32 / (8 per thread * 256 thr)
#define RP_BLOCKS_   513  // ceil((ROWS_+1)/256)
#define OUT1_BLOCKS_ 32768 // ROWS_*64 f32x4 / 256 thr
#define TOKB_OFF_ (1u << 20)   // fp8 tok copy at d_ws + 1 MiB (12.8 MB)

typedef float f32x2 __attribute__((ext_vector_type(2)));
typedef float f32x4 __attribute__((ext_vector_type(4)));
typedef unsigned int u32x2 __attribute__((ext_vector_type(2)));

// Streaming store: nt (non-temporal) + sc1 — attempt to stop the output
// write streams from allocating in the memory-side Infinity Cache, so the
// 12.8 MB fp8 tok table stays IC-resident for K2's gathers. (R5 showed nt
// alone ~null; sc1 is the untried policy bit.)
__device__ __forceinline__ void store_stream(f32x4 v, f32x4* p) {
    asm volatile("global_store_dwordx4 %0, %1, off nt sc1"
                 :: "v"(p), "v"(v) : "memory");
}

// ---------------------------------------------------------------------------
// K1 — conv (tok f32 -> fp8 e4m3, HW RNE) || row_ptr || out1 writes.
// Structure identical to round 10; only out1's store policy changed.
// ---------------------------------------------------------------------------
__global__ __launch_bounds__(256) void k1_kernel(
    const int*   __restrict__ rows,
    int*         __restrict__ row_start,
    const f32x4* __restrict__ tok_f32,
    u32x2*       __restrict__ tok_fp8,     // 8 fp8 per thread-slot
    const int*   __restrict__ node_idx,
    const f32x4* __restrict__ w,
    f32x4*       __restrict__ out1) {

    int bid = blockIdx.x;
    if (bid < CONV_BLOCKS_) {
        int t = bid * 256 + threadIdx.x;               // 8 floats each
        f32x4 a = __builtin_nontemporal_load(&tok_f32[2 * t]);
        f32x4 b = __builtin_nontemporal_load(&tok_f32[2 * t + 1]);
        unsigned w0 = __builtin_amdgcn_cvt_pk_fp8_f32(a[0], a[1], 0, false);
        w0          = __builtin_amdgcn_cvt_pk_fp8_f32(a[2], a[3], w0, true);
        unsigned w1 = __builtin_amdgcn_cvt_pk_fp8_f32(b[0], b[1], 0, false);
        w1          = __builtin_amdgcn_cvt_pk_fp8_f32(b[2], b[3], w1, true);
        u32x2 o; o[0] = w0; o[1] = w1;
        tok_fp8[t] = o;                                // normal store: KEEP cached
    } else if (bid < CONV_BLOCKS_ + RP_BLOCKS_) {
        int r = (bid - CONV_BLOCKS_) * 256 + threadIdx.x;
        if (r > ROWS_) return;
        int lo = 0, hi = NNZ_;
        #pragma unroll
        for (int it = 0; it < LOG2NNZ_; ++it) {
            int mid = (lo + hi) >> 1;
            if (rows[mid] < r) lo = mid + 1; else hi = mid;
        }
        row_start[r] = lo;
    } else {
        int tid  = (bid - CONV_BLOCKS_ - RP_BLOCKS_) * 256 + threadIdx.x;
        int row  = tid >> 6;
        int l    = tid & 63;
        int node = node_idx[row];                      // wave-uniform
        f32x4 t0 = w[node * E4_ + l];                  // 128 KiB table, L2-hit
        store_stream(t0, &out1[tid]);
    }
}

// ---------------------------------------------------------------------------
// K2 — SpMM: one wave per output row; 256 B fp8 gathers, x4-unrolled.
// Only the out2 store policy changed vs round 10.
// ---------------------------------------------------------------------------
__global__ __launch_bounds__(256) void spmm_kernel(
    const int*      __restrict__ row_start,
    const int*      __restrict__ cols,
    const float*    __restrict__ vals,
    const unsigned* __restrict__ tokf8,    // u32 = 4 fp8; row stride 64
    f32x4*          __restrict__ out2) {

    int gtid = blockIdx.x * blockDim.x + threadIdx.x;
    int row  = gtid >> 6;
    int lane = threadIdx.x & 63;

    int start = row_start[row];
    int end   = row_start[row + 1];
    int cnt   = end - start;

    f32x4 acc = (f32x4)(0.f);
    for (int base = 0; base < cnt; base += 64) {
        int rem = cnt - base;
        int nn  = rem > 64 ? 64 : rem;
        int idx = start + base + lane;
        bool valid = lane < nn;
        int   c_l = valid ? cols[idx] : 0;     // pad: col 0, val 0
        float v_l = valid ? vals[idx] : 0.f;

        for (int j = 0; j < nn; j += 4) {
            int   ca = __builtin_amdgcn_readlane(c_l, j);
            int   cb = __builtin_amdgcn_readlane(c_l, j + 1);
            int   cc = __builtin_amdgcn_readlane(c_l, j + 2);
            int   cd = __builtin_amdgcn_readlane(c_l, j + 3);
            float va = __int_as_float(__builtin_amdgcn_readlane(__float_as_int(v_l), j));
            float vb = __int_as_float(__builtin_amdgcn_readlane(__float_as_int(v_l), j + 1));
            float vc = __int_as_float(__builtin_amdgcn_readlane(__float_as_int(v_l), j + 2));
            float vd = __int_as_float(__builtin_amdgcn_readlane(__float_as_int(v_l), j + 3));

            // 4 independent 256 B gathers in flight
            unsigned ga = tokf8[(size_t)ca * 64 + lane];
            unsigned gb = tokf8[(size_t)cb * 64 + lane];
            unsigned gc = tokf8[(size_t)cc * 64 + lane];
            unsigned gd = tokf8[(size_t)cd * 64 + lane];

            f32x2 al = __builtin_amdgcn_cvt_pk_f32_fp8(ga, false);
            f32x2 ah = __builtin_amdgcn_cvt_pk_f32_fp8(ga, true);
            f32x2 bl = __builtin_amdgcn_cvt_pk_f32_fp8(gb, false);
            f32x2 bh = __builtin_amdgcn_cvt_pk_f32_fp8(gb, true);
            f32x2 cl = __builtin_amdgcn_cvt_pk_f32_fp8(gc, false);
            f32x2 ch = __builtin_amdgcn_cvt_pk_f32_fp8(gc, true);
            f32x2 dl = __builtin_amdgcn_cvt_pk_f32_fp8(gd, false);
            f32x2 dh = __builtin_amdgcn_cvt_pk_f32_fp8(gd, true);

            acc[0] += va * al[0]; acc[1] += va * al[1];
            acc[2] += va * ah[0]; acc[3] += va * ah[1];
            acc[0] += vb * bl[0]; acc[1] += vb * bl[1];
            acc[2] += vb * bh[0]; acc[3] += vb * bh[1];
            acc[0] += vc * cl[0]; acc[1] += vc * cl[1];
            acc[2] += vc * ch[0]; acc[3] += vc * ch[1];
            acc[0] += vd * dl[0]; acc[1] += vd * dl[1];
            acc[2] += vd * dh[0]; acc[3] += vd * dh[1];
        }
    }
    store_stream(acc, &out2[(size_t)row * E4_ + lane]);
}

extern "C" void kernel_launch(void* const* d_in, const int* in_sizes, int n_in,
                              void* d_out, int out_size, void* d_ws, size_t ws_size,
                              hipStream_t stream) {
    const int*   node_idx  = (const int*)d_in[0];
    const int*   spmm_rows = (const int*)d_in[1];
    const int*   spmm_cols = (const int*)d_in[2];
    const float* spmm_vals = (const float*)d_in[3];
    const float* node_w    = (const float*)d_in[4];
    const float* tok       = (const float*)d_in[5];

    f32x4* out1 = (f32x4*)d_out;                     // node_embed
    f32x4* out2 = out1 + (size_t)ROWS_ * E4_;        // node_val_embed
    int*   row_start = (int*)d_ws;                   // (ROWS_+1) ints
    u32x2* tok_fp8   = (u32x2*)((char*)d_ws + TOKB_OFF_);  // 12.8 MB

    k1_kernel<<<CONV_BLOCKS_ + RP_BLOCKS_ + OUT1_BLOCKS_, 256, 0, stream>>>(
        spmm_rows, row_start, (const f32x4*)tok, tok_fp8,
        node_idx, (const f32x4*)node_w, out1);

    // one wave per row, 4 waves per block -> 32768 blocks
    spmm_kernel<<<ROWS_ / 4, 256, 0, stream>>>(
        row_start, spmm_cols, spmm_vals, (const unsigned*)tok_fp8, out2);
}

// Round 12
// 75.991 us; speedup vs baseline: 1.0637x; 1.0637x over previous
//
#include <hip/hip_runtime.h>

#define ROWS_ 131072      // S*N*B = 16*256*32
#define NNZ_  524288
#define E4_   64          // f32x4 per output row (E=256)
#define LOG2NNZ_ 19       // 2^19 == NNZ_
#define CONV_BLOCKS_ 6250 // 50000*256 f32 / (8 per thread * 256 thr)
#define RP_BLOCKS_   513  // ceil((ROWS_+1)/256)
#define OUT1_BLOCKS_ 32768 // ROWS_*64 f32x4 / 256 thr
#define TOKB_OFF_ (1u << 20)   // fp8 tok copy at d_ws + 1 MiB (12.8 MB)

typedef float f32x2 __attribute__((ext_vector_type(2)));
typedef float f32x4 __attribute__((ext_vector_type(4)));
typedef unsigned int u32x2 __attribute__((ext_vector_type(2)));

// ---------------------------------------------------------------------------
// K1 — conv (tok f32 -> fp8 e4m3, HW RNE) || row_ptr || out1 writes.
// Block-range split so the conversion read stream hides under out1's write
// stream. (R11 lesson: nt/sc1 streaming stores REGRESS — plain nt stores.)
// ---------------------------------------------------------------------------
__global__ __launch_bounds__(256) void k1_kernel(
    const int*   __restrict__ rows,
    int*         __restrict__ row_start,
    const f32x4* __restrict__ tok_f32,
    u32x2*       __restrict__ tok_fp8,     // 8 fp8 per thread-slot
    const int*   __restrict__ node_idx,
    const f32x4* __restrict__ w,
    f32x4*       __restrict__ out1) {

    int bid = blockIdx.x;
    if (bid < CONV_BLOCKS_) {
        int t = bid * 256 + threadIdx.x;               // 8 floats each
        f32x4 a = __builtin_nontemporal_load(&tok_f32[2 * t]);
        f32x4 b = __builtin_nontemporal_load(&tok_f32[2 * t + 1]);
        unsigned w0 = __builtin_amdgcn_cvt_pk_fp8_f32(a[0], a[1], 0, false);
        w0          = __builtin_amdgcn_cvt_pk_fp8_f32(a[2], a[3], w0, true);
        unsigned w1 = __builtin_amdgcn_cvt_pk_fp8_f32(b[0], b[1], 0, false);
        w1          = __builtin_amdgcn_cvt_pk_fp8_f32(b[2], b[3], w1, true);
        u32x2 o; o[0] = w0; o[1] = w1;
        tok_fp8[t] = o;                                // normal store: keep cached
    } else if (bid < CONV_BLOCKS_ + RP_BLOCKS_) {
        int r = (bid - CONV_BLOCKS_) * 256 + threadIdx.x;
        if (r > ROWS_) return;
        int lo = 0, hi = NNZ_;
        #pragma unroll
        for (int it = 0; it < LOG2NNZ_; ++it) {
            int mid = (lo + hi) >> 1;
            if (rows[mid] < r) lo = mid + 1; else hi = mid;
        }
        row_start[r] = lo;
    } else {
        int tid  = (bid - CONV_BLOCKS_ - RP_BLOCKS_) * 256 + threadIdx.x;
        int row  = tid >> 6;
        int l    = tid & 63;
        int node = node_idx[row];                      // wave-uniform
        f32x4 t0 = w[node * E4_ + l];                  // 128 KiB table, L2-hit
        __builtin_nontemporal_store(t0, &out1[tid]);
    }
}

// ---------------------------------------------------------------------------
// K2 — SpMM: one wave per output row; 256 B fp8 gathers (u32 = 4 fp8 per
// lane), x4-unrolled independent gathers via readlane broadcast of (col,val).
// ---------------------------------------------------------------------------
__global__ __launch_bounds__(256) void spmm_kernel(
    const int*      __restrict__ row_start,
    const int*      __restrict__ cols,
    const float*    __restrict__ vals,
    const unsigned* __restrict__ tokf8,    // u32 = 4 fp8; row stride 64
    f32x4*          __restrict__ out2) {

    int gtid = blockIdx.x * blockDim.x + threadIdx.x;
    int row  = gtid >> 6;
    int lane = threadIdx.x & 63;

    int start = row_start[row];
    int end   = row_start[row + 1];
    int cnt   = end - start;

    f32x4 acc = (f32x4)(0.f);
    for (int base = 0; base < cnt; base += 64) {
        int rem = cnt - base;
        int nn  = rem > 64 ? 64 : rem;
        int idx = start + base + lane;
        bool valid = lane < nn;
        int   c_l = valid ? cols[idx] : 0;     // pad: col 0, val 0
        float v_l = valid ? vals[idx] : 0.f;

        for (int j = 0; j < nn; j += 4) {
            int   ca = __builtin_amdgcn_readlane(c_l, j);
            int   cb = __builtin_amdgcn_readlane(c_l, j + 1);
            int   cc = __builtin_amdgcn_readlane(c_l, j + 2);
            int   cd = __builtin_amdgcn_readlane(c_l, j + 3);
            float va = __int_as_float(__builtin_amdgcn_readlane(__float_as_int(v_l), j));
            float vb = __int_as_float(__builtin_amdgcn_readlane(__float_as_int(v_l), j + 1));
            float vc = __int_as_float(__builtin_amdgcn_readlane(__float_as_int(v_l), j + 2));
            float vd = __int_as_float(__builtin_amdgcn_readlane(__float_as_int(v_l), j + 3));

            // 4 independent 256 B gathers in flight
            unsigned ga = tokf8[(size_t)ca * 64 + lane];
            unsigned gb = tokf8[(size_t)cb * 64 + lane];
            unsigned gc = tokf8[(size_t)cc * 64 + lane];
            unsigned gd = tokf8[(size_t)cd * 64 + lane];

            f32x2 al = __builtin_amdgcn_cvt_pk_f32_fp8(ga, false);
            f32x2 ah = __builtin_amdgcn_cvt_pk_f32_fp8(ga, true);
            f32x2 bl = __builtin_amdgcn_cvt_pk_f32_fp8(gb, false);
            f32x2 bh = __builtin_amdgcn_cvt_pk_f32_fp8(gb, true);
            f32x2 cl = __builtin_amdgcn_cvt_pk_f32_fp8(gc, false);
            f32x2 ch = __builtin_amdgcn_cvt_pk_f32_fp8(gc, true);
            f32x2 dl = __builtin_amdgcn_cvt_pk_f32_fp8(gd, false);
            f32x2 dh = __builtin_amdgcn_cvt_pk_f32_fp8(gd, true);

            acc[0] += va * al[0]; acc[1] += va * al[1];
            acc[2] += va * ah[0]; acc[3] += va * ah[1];
            acc[0] += vb * bl[0]; acc[1] += vb * bl[1];
            acc[2] += vb * bh[0]; acc[3] += vb * bh[1];
            acc[0] += vc * cl[0]; acc[1] += vc * cl[1];
            acc[2] += vc * ch[0]; acc[3] += vc * ch[1];
            acc[0] += vd * dl[0]; acc[1] += vd * dl[1];
            acc[2] += vd * dh[0]; acc[3] += vd * dh[1];
        }
    }
    __builtin_nontemporal_store(acc, &out2[(size_t)row * E4_ + lane]);
}

extern "C" void kernel_launch(void* const* d_in, const int* in_sizes, int n_in,
                              void* d_out, int out_size, void* d_ws, size_t ws_size,
                              hipStream_t stream) {
    const int*   node_idx  = (const int*)d_in[0];
    const int*   spmm_rows = (const int*)d_in[1];
    const int*   spmm_cols = (const int*)d_in[2];
    const float* spmm_vals = (const float*)d_in[3];
    const float* node_w    = (const float*)d_in[4];
    const float* tok       = (const float*)d_in[5];

    f32x4* out1 = (f32x4*)d_out;                     // node_embed
    f32x4* out2 = out1 + (size_t)ROWS_ * E4_;        // node_val_embed
    int*   row_start = (int*)d_ws;                   // (ROWS_+1) ints
    u32x2* tok_fp8   = (u32x2*)((char*)d_ws + TOKB_OFF_);  // 12.8 MB

    k1_kernel<<<CONV_BLOCKS_ + RP_BLOCKS_ + OUT1_BLOCKS_, 256, 0, stream>>>(
        spmm_rows, row_start, (const f32x4*)tok, tok_fp8,
        node_idx, (const f32x4*)node_w, out1);

    // one wave per row, 4 waves per block -> 32768 blocks
    spmm_kernel<<<ROWS_ / 4, 256, 0, stream>>>(
        row_start, spmm_cols, spmm_vals, (const unsigned*)tok_fp8, out2);
}